// Round 2
// baseline (1129.608 us; speedup 1.0000x reference)
//
#include <hip/hip_runtime.h>

#define SEQ 4096
#define TOK 16384            // B*S
#define DM 1024
#define NQKV 3072
#define FFH 2730
#define FFHP 2816            // padded to multiple of 128

typedef __bf16 bf16x8 __attribute__((ext_vector_type(8)));
typedef float f32x4 __attribute__((ext_vector_type(4)));

__device__ __forceinline__ unsigned short f2bf(float f) {
  union { float f; unsigned u; } v; v.f = f;
  unsigned r = v.u + 0x7fffu + ((v.u >> 16) & 1u);
  return (unsigned short)(r >> 16);
}
__device__ __forceinline__ float bf2f(unsigned short h) {
  union { unsigned u; float f; } v; v.u = ((unsigned)h) << 16;
  return v.f;
}

enum { M_QKV = 0, M_BF16 = 1, M_F32 = 2, M_BIAS_BF16 = 3, M_SWIGLU = 4, M_BIAS_F32 = 5 };

// C[M,N] = A[M,K] (row-major) * BT[N,K]^T, 128x128 tile, BK=64, 4 waves,
// mfma_f32_16x16x32_bf16, global_load_lds(16B) staging.
template<int MODE>
__global__ __launch_bounds__(256)
void gemm_kernel(const unsigned short* __restrict__ A,
                 const unsigned short* __restrict__ BT,
                 int K, int lda, int ldb, int ldc,
                 long zsA, long zsB, long zsC,
                 void* __restrict__ out0, void* __restrict__ out1, void* __restrict__ out2,
                 const float* __restrict__ bias, int nbias)
{
  __shared__ unsigned short As[128 * 64];
  __shared__ unsigned short Bs[128 * 64];
  const int tid  = threadIdx.x;
  const int wave = tid >> 6, lane = tid & 63;
  const int quad = lane >> 4, l16 = lane & 15;
  const int bx = blockIdx.x, by = blockIdx.y, bz = blockIdx.z;
  const unsigned short* Ab = A + (size_t)zsA * bz + (size_t)by * 128 * lda;
  const unsigned short* Bb = BT + (size_t)zsB * bz + (size_t)bx * 128 * ldb;

  f32x4 acc[4][4] = {};

  const int srow = lane >> 3;        // 0..7 within 8-row chunk
  const int scol = (lane & 7) * 8;   // 0..56, 8 bf16 = 16B

  for (int k0 = 0; k0 < K; k0 += 64) {
    if (k0) __syncthreads();
#pragma unroll
    for (int j = 0; j < 4; ++j) {
      int c = wave * 4 + j;          // 16 chunks of 8 rows
      const unsigned short* sa = Ab + (size_t)(c * 8 + srow) * lda + k0 + scol;
      __builtin_amdgcn_global_load_lds((__attribute__((address_space(1))) void*)sa,
          (__attribute__((address_space(3))) void*)(As + c * 512), 16, 0, 0);
      const unsigned short* sb = Bb + (size_t)(c * 8 + srow) * ldb + k0 + scol;
      __builtin_amdgcn_global_load_lds((__attribute__((address_space(1))) void*)sb,
          (__attribute__((address_space(3))) void*)(Bs + c * 512), 16, 0, 0);
    }
    __builtin_amdgcn_s_waitcnt(0);
    __syncthreads();
#pragma unroll
    for (int kk = 0; kk < 64; kk += 32) {
      bf16x8 af[4], bfr[4];
#pragma unroll
      for (int mt = 0; mt < 4; ++mt)
        af[mt] = *(const bf16x8*)(As + ((wave >> 1) * 64 + mt * 16 + l16) * 64 + kk + quad * 8);
#pragma unroll
      for (int nt = 0; nt < 4; ++nt)
        bfr[nt] = *(const bf16x8*)(Bs + ((wave & 1) * 64 + nt * 16 + l16) * 64 + kk + quad * 8);
#pragma unroll
      for (int mt = 0; mt < 4; ++mt)
#pragma unroll
        for (int nt = 0; nt < 4; ++nt)
          acc[mt][nt] = __builtin_amdgcn_mfma_f32_16x16x32_bf16(af[mt], bfr[nt], acc[mt][nt], 0, 0, 0);
    }
  }

#pragma unroll
  for (int mt = 0; mt < 4; ++mt) {
#pragma unroll
    for (int nt = 0; nt < 4; ++nt) {
      const int r0 = by * 128 + (wave >> 1) * 64 + mt * 16 + quad * 4;
      const int c  = bx * 128 + (wave & 1) * 64 + nt * 16 + l16;
      float vals[4];
#pragma unroll
      for (int i = 0; i < 4; ++i) vals[i] = acc[mt][nt][i];

      if (MODE == M_QKV) {
        // out0 = qp [b*s][d]  (elu+1)
        // out1 = kpT [b][d][s] (elu+1, transposed)
        // out2 = vT  [b][d][s] (transposed)
        const int b = r0 >> 12, s0 = r0 & 4095;
#pragma unroll
        for (int i = 0; i < 4; ++i) vals[i] += bias[c];
        if (c < 1024) {
#pragma unroll
          for (int i = 0; i < 4; ++i) {
            float e = vals[i] > 0.f ? vals[i] + 1.f : __expf(vals[i]);
            ((unsigned short*)out0)[(size_t)(r0 + i) * DM + c] = f2bf(e);
          }
        } else if (c < 2048) {
          ushort4 o;
          float e0 = vals[0] > 0.f ? vals[0] + 1.f : __expf(vals[0]);
          float e1 = vals[1] > 0.f ? vals[1] + 1.f : __expf(vals[1]);
          float e2 = vals[2] > 0.f ? vals[2] + 1.f : __expf(vals[2]);
          float e3 = vals[3] > 0.f ? vals[3] + 1.f : __expf(vals[3]);
          o.x = f2bf(e0); o.y = f2bf(e1); o.z = f2bf(e2); o.w = f2bf(e3);
          *(ushort4*)((unsigned short*)out1 + (size_t)b * DM * SEQ + (size_t)(c - 1024) * SEQ + s0) = o;
        } else {
          ushort4 o;
          o.x = f2bf(vals[0]); o.y = f2bf(vals[1]); o.z = f2bf(vals[2]); o.w = f2bf(vals[3]);
          *(ushort4*)((unsigned short*)out2 + (size_t)b * DM * SEQ + (size_t)(c - 2048) * SEQ + s0) = o;
        }
      } else {
#pragma unroll
        for (int i = 0; i < 4; ++i) {
          const int r = r0 + i;
          float val = vals[i];
          if (MODE == M_BF16) {
            ((unsigned short*)out0)[(size_t)zsC * bz + (size_t)r * ldc + c] = f2bf(val);
          } else if (MODE == M_F32) {
            ((float*)out0)[(size_t)zsC * bz + (size_t)r * ldc + c] = val;
          } else if (MODE == M_BIAS_BF16) {
            if (c < nbias) val += bias[c];
            ((unsigned short*)out0)[(size_t)r * ldc + c] = f2bf(val);
          } else if (MODE == M_SWIGLU) {
            if (c < nbias) val += bias[c];
            float g = bf2f(((const unsigned short*)out1)[(size_t)r * ldc + c]);
            float h = g / (1.f + __expf(-g)) * val;
            ((unsigned short*)out0)[(size_t)r * ldc + c] = f2bf(h);
          } else { // M_BIAS_F32
            if (c < nbias) val += bias[c];
            ((float*)out0)[(size_t)r * ldc + c] = val;
          }
        }
      }
    }
  }
}

// fp32 -> bf16 convert, 4 elems/thread
__global__ __launch_bounds__(256)
void cvt_kernel(const float* __restrict__ in, unsigned short* __restrict__ out, int n)
{
  int i = (blockIdx.x * 256 + threadIdx.x) * 4;
  if (i < n) {
    float4 v = *(const float4*)(in + i);
    ushort4 o;
    o.x = f2bf(v.x); o.y = f2bf(v.y); o.z = f2bf(v.z); o.w = f2bf(v.w);
    *(ushort4*)(out + i) = o;
  }
}

// in fp32 [R][C] -> out bf16 [Cpad][Rpad], zero-filled pad. grid (Rpad/32, Cpad/32)
__global__ __launch_bounds__(256)
void wtrans_kernel(const float* __restrict__ in, unsigned short* __restrict__ out,
                   int R, int C, int Cpad, int Rpad)
{
  __shared__ float tile[32][33];
  int r0 = blockIdx.x * 32;   // in-row / out-col
  int c0 = blockIdx.y * 32;   // in-col / out-row
  int tid = threadIdx.x;
#pragma unroll
  for (int j = 0; j < 4; ++j) {
    int r = j * 8 + (tid >> 5), c = tid & 31;
    float v = 0.f;
    if (r0 + r < R && c0 + c < C) v = in[(size_t)(r0 + r) * C + c0 + c];
    tile[r][c] = v;
  }
  __syncthreads();
#pragma unroll
  for (int j = 0; j < 4; ++j) {
    int c = j * 8 + (tid >> 5), r = tid & 31;
    out[(size_t)(c0 + c) * Rpad + (r0 + r)] = f2bf(tile[r][c]);
  }
}

__device__ __forceinline__ float block_sum(float v, float* sm)
{
#pragma unroll
  for (int o = 32; o > 0; o >>= 1) v += __shfl_down(v, o, 64);
  int w = threadIdx.x >> 6;
  if ((threadIdx.x & 63) == 0) sm[w] = v;
  __syncthreads();
  float r = sm[0] + sm[1] + sm[2] + sm[3];
  __syncthreads();
  return r;
}

// row sums of kpT [4][1024][4096] -> ksum [4][1024]; grid 4096
__global__ __launch_bounds__(256)
void ksum_kernel(const unsigned short* __restrict__ kpT, float* __restrict__ ksum)
{
  __shared__ float sm[4];
  int row = blockIdx.x;
  const ushort4* src = (const ushort4*)(kpT + (size_t)row * SEQ);
  float s = 0.f;
#pragma unroll
  for (int j = 0; j < 4; ++j) {
    ushort4 v = src[threadIdx.x + j * 256];
    s += bf2f(v.x) + bf2f(v.y) + bf2f(v.z) + bf2f(v.w);
  }
  float tot = block_sum(s, sm);
  if (threadIdx.x == 0) ksum[row] = tot;
}

// y = LN(x + num/(den+eps)); den = qp . ksum  (fused). grid TOK, 256 thr
__global__ __launch_bounds__(256)
void ln1_kernel(const float* __restrict__ x, const float* __restrict__ num,
                const unsigned short* __restrict__ qp, const float* __restrict__ ksum,
                const float* __restrict__ g1, const float* __restrict__ b1,
                unsigned short* __restrict__ yb)
{
  __shared__ float sm[4];
  int t = blockIdx.x, tid = threadIdx.x, b = t >> 12;
  float4 xv = ((const float4*)(x + (size_t)t * DM))[tid];
  float4 nv = ((const float4*)(num + (size_t)t * DM))[tid];
  ushort4 qv = ((const ushort4*)(qp + (size_t)t * DM))[tid];
  float4 kv = ((const float4*)(ksum + (size_t)b * DM))[tid];
  float q0 = bf2f(qv.x), q1 = bf2f(qv.y), q2 = bf2f(qv.z), q3 = bf2f(qv.w);
  float den = block_sum(q0 * kv.x + q1 * kv.y + q2 * kv.z + q3 * kv.w, sm);
  float inv = 1.f / (den + 1e-6f);
  float r0 = xv.x + nv.x * inv, r1 = xv.y + nv.y * inv;
  float r2 = xv.z + nv.z * inv, r3 = xv.w + nv.w * inv;
  float s1 = block_sum(r0 + r1 + r2 + r3, sm);
  float s2 = block_sum(r0 * r0 + r1 * r1 + r2 * r2 + r3 * r3, sm);
  float mu = s1 * (1.f / 1024.f);
  float var = s2 * (1.f / 1024.f) - mu * mu;
  float rs = rsqrtf(var + 1e-5f);
  float4 gv = ((const float4*)g1)[tid];
  float4 bv = ((const float4*)b1)[tid];
  ushort4 o;
  o.x = f2bf((r0 - mu) * rs * gv.x + bv.x);
  o.y = f2bf((r1 - mu) * rs * gv.y + bv.y);
  o.z = f2bf((r2 - mu) * rs * gv.z + bv.z);
  o.w = f2bf((r3 - mu) * rs * gv.w + bv.w);
  ((ushort4*)(yb + (size_t)t * DM))[tid] = o;
}

// out = LN(y + ffn). grid TOK, 256 thr. ffn may alias out (row-local).
__global__ __launch_bounds__(256)
void ln2_kernel(const unsigned short* __restrict__ yb, const float* __restrict__ ffn,
                const float* __restrict__ g2, const float* __restrict__ b2,
                float* __restrict__ out)
{
  __shared__ float sm[4];
  int t = blockIdx.x, tid = threadIdx.x;
  ushort4 yv = ((const ushort4*)(yb + (size_t)t * DM))[tid];
  float4 fv = ((const float4*)(ffn + (size_t)t * DM))[tid];
  float r0 = bf2f(yv.x) + fv.x, r1 = bf2f(yv.y) + fv.y;
  float r2 = bf2f(yv.z) + fv.z, r3 = bf2f(yv.w) + fv.w;
  float s1 = block_sum(r0 + r1 + r2 + r3, sm);
  float s2 = block_sum(r0 * r0 + r1 * r1 + r2 * r2 + r3 * r3, sm);
  float mu = s1 * (1.f / 1024.f);
  float var = s2 * (1.f / 1024.f) - mu * mu;
  float rs = rsqrtf(var + 1e-5f);
  float4 gv = ((const float4*)g2)[tid];
  float4 bv = ((const float4*)b2)[tid];
  float4 o;
  o.x = (r0 - mu) * rs * gv.x + bv.x;
  o.y = (r1 - mu) * rs * gv.y + bv.y;
  o.z = (r2 - mu) * rs * gv.z + bv.z;
  o.w = (r3 - mu) * rs * gv.w + bv.w;
  ((float4*)(out + (size_t)t * DM))[tid] = o;
}

extern "C" void kernel_launch(void* const* d_in, const int* in_sizes, int n_in,
                              void* d_out, int out_size, void* d_ws, size_t ws_size,
                              hipStream_t stream)
{
  const float* x    = (const float*)d_in[0];
  const float* Wqkv = (const float*)d_in[1];
  const float* bqkv = (const float*)d_in[2];
  const float* Wg   = (const float*)d_in[3];
  const float* bg   = (const float*)d_in[4];
  const float* Wu   = (const float*)d_in[5];
  const float* bu   = (const float*)d_in[6];
  const float* Wd   = (const float*)d_in[7];
  const float* bd   = (const float*)d_in[8];
  const float* g1   = (const float*)d_in[9];
  const float* b1   = (const float*)d_in[10];
  const float* g2   = (const float*)d_in[11];
  const float* b2   = (const float*)d_in[12];
  float* out = (float*)d_out;

  // ---- workspace layout (~158.5 MiB total) ----
  char* ws = (char*)d_ws;
  size_t off = 0;
  auto alloc = [&](size_t bytes) {
    char* p = ws + off;
    off += (bytes + 255) & ~(size_t)255;
    return p;
  };
  unsigned short* WqkvT = (unsigned short*)alloc((size_t)NQKV * DM * 2);   //  6.3 MB
  unsigned short* WgT   = (unsigned short*)alloc((size_t)FFHP * DM * 2);   //  5.8 MB
  unsigned short* WuT   = (unsigned short*)alloc((size_t)FFHP * DM * 2);   //  5.8 MB
  unsigned short* WdT   = (unsigned short*)alloc((size_t)DM * FFHP * 2);   //  5.8 MB
  float*          ksum  = (float*)alloc((size_t)4 * DM * 4);               // 16 KB
  unsigned short* xbyb  = (unsigned short*)alloc((size_t)TOK * DM * 2);    // 32 MB (xb then yb)
  unsigned short* kvT   = (unsigned short*)alloc((size_t)4 * DM * DM * 2); //  8.4 MB
  char* R3 = alloc((size_t)3 * TOK * DM * 2);                              // 96 MB
  unsigned short* qp  = (unsigned short*)(R3);
  unsigned short* kpT = (unsigned short*)(R3 + (size_t)TOK * DM * 2);
  unsigned short* vT  = (unsigned short*)(R3 + (size_t)2 * TOK * DM * 2);
  unsigned short* gate = (unsigned short*)(R3);     // aliases qp/kpT (dead after ln1); 92.3 MB
  unsigned short* xb = xbyb;                        // dead after QKV GEMM
  unsigned short* yb = xbyb;                        // born at ln1
  float* num = (float*)d_out;                       // fp32 scratch; dead after ln1
  float* ffn = (float*)d_out;                       // fp32 scratch; ln2 reads+overwrites row-local

  dim3 blk(256);

  // 1. x -> bf16
  cvt_kernel<<<dim3(TOK * DM / 1024), blk, 0, stream>>>(x, xb, TOK * DM);
  // 2. weight transpose+convert (+pad)
  wtrans_kernel<<<dim3(32, 96), blk, 0, stream>>>(Wqkv, WqkvT, 1024, 3072, 3072, 1024);
  wtrans_kernel<<<dim3(32, 88), blk, 0, stream>>>(Wg, WgT, 1024, FFH, FFHP, 1024);
  wtrans_kernel<<<dim3(32, 88), blk, 0, stream>>>(Wu, WuT, 1024, FFH, FFHP, 1024);
  wtrans_kernel<<<dim3(88, 32), blk, 0, stream>>>(Wd, WdT, FFH, 1024, 1024, FFHP);
  // 3. QKV GEMM: qp[s][d] (elu+1), kpT[d][s] (elu+1), vT[d][s]
  gemm_kernel<M_QKV><<<dim3(NQKV / 128, TOK / 128), blk, 0, stream>>>(
      xb, WqkvT, 1024, 1024, 1024, 0, 0, 0, 0, qp, kpT, vT, bqkv, NQKV);
  // 4. k_sum[b][d]
  ksum_kernel<<<dim3(4096), blk, 0, stream>>>(kpT, ksum);
  // 5. kvT[b][e][d] = sum_s v[s,e] kp[s,d]
  gemm_kernel<M_BF16><<<dim3(8, 8, 4), blk, 0, stream>>>(
      vT, kpT, 4096, 4096, 4096, 1024,
      (long)DM * SEQ, (long)DM * SEQ, (long)DM * DM,
      kvT, nullptr, nullptr, nullptr, 0);
  // 6. num[b][s][e] = qp[s,:] . kv[:,e]  (BT = kvT) -> d_out (fp32)
  gemm_kernel<M_F32><<<dim3(8, 32, 4), blk, 0, stream>>>(
      qp, kvT, 1024, 1024, 1024, 1024,
      (long)SEQ * DM, (long)DM * DM, (long)SEQ * DM,
      num, nullptr, nullptr, nullptr, 0);
  // 7. LN1 (fused den + attn + residual), y in bf16 (overwrites xb)
  ln1_kernel<<<dim3(TOK), blk, 0, stream>>>(x, num, qp, ksum, g1, b1, yb);
  // 8. gate = y @ Wg + bg (bf16), into R3 (phase-1 buffers dead)
  gemm_kernel<M_BIAS_BF16><<<dim3(FFHP / 128, TOK / 128), blk, 0, stream>>>(
      yb, WgT, 1024, 1024, 1024, FFHP, 0, 0, 0, gate, nullptr, nullptr, bg, FFH);
  // 9. h = silu(gate) * (y @ Wu + bu), in-place over gate
  gemm_kernel<M_SWIGLU><<<dim3(FFHP / 128, TOK / 128), blk, 0, stream>>>(
      yb, WuT, 1024, 1024, 1024, FFHP, 0, 0, 0, gate, gate, nullptr, bu, FFH);
  // 10. ffn = h @ Wd + bd (fp32) -> d_out
  gemm_kernel<M_BIAS_F32><<<dim3(DM / 128, TOK / 128), blk, 0, stream>>>(
      gate, WdT, FFHP, FFHP, FFHP, DM, 0, 0, 0, ffn, nullptr, nullptr, bd, DM);
  // 11. out = LN(y + ffn)  (reads+overwrites d_out row-locally)
  ln2_kernel<<<dim3(TOK), blk, 0, stream>>>(yb, ffn, g2, b2, out);

  (void)in_sizes; (void)n_in; (void)out_size; (void)ws_size;
}

// Round 3
// 996.721 us; speedup vs baseline: 1.1333x; 1.1333x over previous
//
#include <hip/hip_runtime.h>

#define SEQ 4096
#define TOK 16384            // B*S
#define DM 1024
#define NQKV 3072
#define FFH 2730
#define FFHP 2816            // padded to multiple of 128

typedef __bf16 bf16x8 __attribute__((ext_vector_type(8)));
typedef float f32x4 __attribute__((ext_vector_type(4)));

__device__ __forceinline__ unsigned short f2bf(float f) {
  union { float f; unsigned u; } v; v.f = f;
  unsigned r = v.u + 0x7fffu + ((v.u >> 16) & 1u);
  return (unsigned short)(r >> 16);
}
__device__ __forceinline__ float bf2f(unsigned short h) {
  union { unsigned u; float f; } v; v.u = ((unsigned)h) << 16;
  return v.f;
}

enum { M_QKV = 0, M_BF16 = 1, M_NUM = 2, M_BIAS_BF16 = 3, M_SWIGLU = 4, M_BIAS_F32 = 5 };

// C[M,N] = A[M,K] (row-major) * BT[N,K]^T, 128x128 tile, BK=64, 4 waves,
// mfma_f32_16x16x32_bf16, global_load_lds(16B) staging.
// XCD swizzle: XCD x owns M-chunk x (A-tile fetched by exactly one XCD's L2).
// XOR bank swizzle: LDS[row][g] holds global k-block (g ^ (row&7)) -> conflict-free b128 reads.
template<int MODE>
__global__ __launch_bounds__(256)
void gemm_kernel(const unsigned short* __restrict__ A,
                 const unsigned short* __restrict__ BT,
                 int K, int lda, int ldb, int ldc,
                 long zsA, long zsB, long zsC,
                 void* __restrict__ out0, void* __restrict__ out1, void* __restrict__ out2,
                 const float* __restrict__ bias, int nbias)
{
  __shared__ unsigned short As[128 * 64];
  __shared__ unsigned short Bs[128 * 64];
  const int tid  = threadIdx.x;
  const int wave = tid >> 6, lane = tid & 63;
  const int quad = lane >> 4, l16 = lane & 15;
  const int bz = blockIdx.z;

  // ---- XCD-aware block swizzle (gy % 8 == 0 in all launches) ----
  int bx = blockIdx.x, by = blockIdx.y;
  {
    const int gx = gridDim.x, gy = gridDim.y;
    const int chunk = gy >> 3;            // power of 2 in all our launches
    const int csh = __ffs(chunk) - 1;
    const int lin = by * gx + bx;
    const int xcd = lin & 7, j = lin >> 3;
    by = xcd * chunk + (j & (chunk - 1));
    bx = j >> csh;
  }

  const unsigned short* Ab = A + (size_t)zsA * bz + (size_t)by * 128 * lda;
  const unsigned short* Bb = BT + (size_t)zsB * bz + (size_t)bx * 128 * ldb;

  f32x4 acc[4][4] = {};

  const int srow   = lane >> 3;                        // 0..7 within 8-row chunk
  const int scol_g = (((lane & 7) ^ srow) * 8);        // XOR-swizzled global col block

  for (int k0 = 0; k0 < K; k0 += 64) {
    if (k0) __syncthreads();
#pragma unroll
    for (int j = 0; j < 4; ++j) {
      int c = wave * 4 + j;          // 16 chunks of 8 rows
      const unsigned short* sa = Ab + (size_t)(c * 8 + srow) * lda + k0 + scol_g;
      __builtin_amdgcn_global_load_lds((__attribute__((address_space(1))) void*)sa,
          (__attribute__((address_space(3))) void*)(As + c * 512), 16, 0, 0);
      const unsigned short* sb = Bb + (size_t)(c * 8 + srow) * ldb + k0 + scol_g;
      __builtin_amdgcn_global_load_lds((__attribute__((address_space(1))) void*)sb,
          (__attribute__((address_space(3))) void*)(Bs + c * 512), 16, 0, 0);
    }
    __builtin_amdgcn_s_waitcnt(0);
    __syncthreads();
    const int axor = l16 & 7;
#pragma unroll
    for (int kk = 0; kk < 64; kk += 32) {
      bf16x8 af[4], bfr[4];
#pragma unroll
      for (int mt = 0; mt < 4; ++mt)
        af[mt] = *(const bf16x8*)(As + ((wave >> 1) * 64 + mt * 16 + l16) * 64
                                     + ((((kk >> 3) + quad) ^ axor) * 8));
#pragma unroll
      for (int nt = 0; nt < 4; ++nt)
        bfr[nt] = *(const bf16x8*)(Bs + ((wave & 1) * 64 + nt * 16 + l16) * 64
                                      + ((((kk >> 3) + quad) ^ axor) * 8));
#pragma unroll
      for (int mt = 0; mt < 4; ++mt)
#pragma unroll
        for (int nt = 0; nt < 4; ++nt)
          acc[mt][nt] = __builtin_amdgcn_mfma_f32_16x16x32_bf16(af[mt], bfr[nt], acc[mt][nt], 0, 0, 0);
    }
  }

#pragma unroll
  for (int mt = 0; mt < 4; ++mt) {
#pragma unroll
    for (int nt = 0; nt < 4; ++nt) {
      const int r0 = by * 128 + (wave >> 1) * 64 + mt * 16 + quad * 4;
      const int c  = bx * 128 + (wave & 1) * 64 + nt * 16 + l16;
      float vals[4];
#pragma unroll
      for (int i = 0; i < 4; ++i) vals[i] = acc[mt][nt][i];

      if (MODE == M_QKV) {
        // out0 = qp [b*s][d]  (elu+1)
        // out1 = kpT [b][d][s] (elu+1, transposed)
        // out2 = vT  [b][d][s] (transposed)
        const int b = r0 >> 12, s0 = r0 & 4095;
#pragma unroll
        for (int i = 0; i < 4; ++i) vals[i] += bias[c];
        if (c < 1024) {
#pragma unroll
          for (int i = 0; i < 4; ++i) {
            float e = vals[i] > 0.f ? vals[i] + 1.f : __expf(vals[i]);
            ((unsigned short*)out0)[(size_t)(r0 + i) * DM + c] = f2bf(e);
          }
        } else if (c < 2048) {
          ushort4 o;
          float e0 = vals[0] > 0.f ? vals[0] + 1.f : __expf(vals[0]);
          float e1 = vals[1] > 0.f ? vals[1] + 1.f : __expf(vals[1]);
          float e2 = vals[2] > 0.f ? vals[2] + 1.f : __expf(vals[2]);
          float e3 = vals[3] > 0.f ? vals[3] + 1.f : __expf(vals[3]);
          o.x = f2bf(e0); o.y = f2bf(e1); o.z = f2bf(e2); o.w = f2bf(e3);
          *(ushort4*)((unsigned short*)out1 + (size_t)b * DM * SEQ + (size_t)(c - 1024) * SEQ + s0) = o;
        } else {
          ushort4 o;
          o.x = f2bf(vals[0]); o.y = f2bf(vals[1]); o.z = f2bf(vals[2]); o.w = f2bf(vals[3]);
          *(ushort4*)((unsigned short*)out2 + (size_t)b * DM * SEQ + (size_t)(c - 2048) * SEQ + s0) = o;
        }
      } else {
#pragma unroll
        for (int i = 0; i < 4; ++i) {
          const int r = r0 + i;
          float val = vals[i];
          if (MODE == M_BF16) {
            ((unsigned short*)out0)[(size_t)zsC * bz + (size_t)r * ldc + c] = f2bf(val);
          } else if (MODE == M_NUM) {
            ((unsigned short*)out0)[(size_t)zsC * bz + (size_t)r * ldc + c] = f2bf(val);
          } else if (MODE == M_BIAS_BF16) {
            if (c < nbias) val += bias[c];
            ((unsigned short*)out0)[(size_t)r * ldc + c] = f2bf(val);
          } else if (MODE == M_SWIGLU) {
            if (c < nbias) val += bias[c];
            float g = bf2f(((const unsigned short*)out1)[(size_t)r * ldc + c]);
            float h = g / (1.f + __expf(-g)) * val;
            ((unsigned short*)out0)[(size_t)r * ldc + c] = f2bf(h);
          } else { // M_BIAS_F32
            if (c < nbias) val += bias[c];
            ((float*)out0)[(size_t)r * ldc + c] = val;
          }
        }
      }
    }
  }
}

// fp32 -> bf16 convert, 4 elems/thread
__global__ __launch_bounds__(256)
void cvt_kernel(const float* __restrict__ in, unsigned short* __restrict__ out, int n)
{
  int i = (blockIdx.x * 256 + threadIdx.x) * 4;
  if (i < n) {
    float4 v = *(const float4*)(in + i);
    ushort4 o;
    o.x = f2bf(v.x); o.y = f2bf(v.y); o.z = f2bf(v.z); o.w = f2bf(v.w);
    *(ushort4*)(out + i) = o;
  }
}

// in fp32 [R][C] -> out bf16 [Cpad][Rpad], zero-filled pad. grid (Rpad/32, Cpad/32)
__global__ __launch_bounds__(256)
void wtrans_kernel(const float* __restrict__ in, unsigned short* __restrict__ out,
                   int R, int C, int Cpad, int Rpad)
{
  __shared__ float tile[32][33];
  int r0 = blockIdx.x * 32;   // in-row / out-col
  int c0 = blockIdx.y * 32;   // in-col / out-row
  int tid = threadIdx.x;
#pragma unroll
  for (int j = 0; j < 4; ++j) {
    int r = j * 8 + (tid >> 5), c = tid & 31;
    float v = 0.f;
    if (r0 + r < R && c0 + c < C) v = in[(size_t)(r0 + r) * C + c0 + c];
    tile[r][c] = v;
  }
  __syncthreads();
#pragma unroll
  for (int j = 0; j < 4; ++j) {
    int c = j * 8 + (tid >> 5), r = tid & 31;
    out[(size_t)(c0 + c) * Rpad + (r0 + r)] = f2bf(tile[r][c]);
  }
}

__device__ __forceinline__ float block_sum(float v, float* sm)
{
#pragma unroll
  for (int o = 32; o > 0; o >>= 1) v += __shfl_down(v, o, 64);
  int w = threadIdx.x >> 6;
  if ((threadIdx.x & 63) == 0) sm[w] = v;
  __syncthreads();
  float r = sm[0] + sm[1] + sm[2] + sm[3];
  __syncthreads();
  return r;
}

// row sums of kpT [4][1024][4096] -> ksum [4][1024]; grid 4096
__global__ __launch_bounds__(256)
void ksum_kernel(const unsigned short* __restrict__ kpT, float* __restrict__ ksum)
{
  __shared__ float sm[4];
  int row = blockIdx.x;
  const ushort4* src = (const ushort4*)(kpT + (size_t)row * SEQ);
  float s = 0.f;
#pragma unroll
  for (int j = 0; j < 4; ++j) {
    ushort4 v = src[threadIdx.x + j * 256];
    s += bf2f(v.x) + bf2f(v.y) + bf2f(v.z) + bf2f(v.w);
  }
  float tot = block_sum(s, sm);
  if (threadIdx.x == 0) ksum[row] = tot;
}

// y = LN(x + num/(den+eps)); den = qp . ksum  (fused). grid TOK, 256 thr
// xb16 (bf16 x) may alias yb: each thread reads its own 4 elems, writes same addr.
__global__ __launch_bounds__(256)
void ln1_kernel(const unsigned short* __restrict__ xb16, const unsigned short* __restrict__ num16,
                const unsigned short* __restrict__ qp, const float* __restrict__ ksum,
                const float* __restrict__ g1, const float* __restrict__ b1,
                unsigned short* __restrict__ yb)
{
  __shared__ float sm[4];
  int t = blockIdx.x, tid = threadIdx.x, b = t >> 12;
  ushort4 xv = ((const ushort4*)(xb16 + (size_t)t * DM))[tid];
  ushort4 nv = ((const ushort4*)(num16 + (size_t)t * DM))[tid];
  ushort4 qv = ((const ushort4*)(qp + (size_t)t * DM))[tid];
  float4 kv = ((const float4*)(ksum + (size_t)b * DM))[tid];
  float q0 = bf2f(qv.x), q1 = bf2f(qv.y), q2 = bf2f(qv.z), q3 = bf2f(qv.w);
  float den = block_sum(q0 * kv.x + q1 * kv.y + q2 * kv.z + q3 * kv.w, sm);
  float inv = 1.f / (den + 1e-6f);
  float r0 = bf2f(xv.x) + bf2f(nv.x) * inv, r1 = bf2f(xv.y) + bf2f(nv.y) * inv;
  float r2 = bf2f(xv.z) + bf2f(nv.z) * inv, r3 = bf2f(xv.w) + bf2f(nv.w) * inv;
  float s1 = block_sum(r0 + r1 + r2 + r3, sm);
  float s2 = block_sum(r0 * r0 + r1 * r1 + r2 * r2 + r3 * r3, sm);
  float mu = s1 * (1.f / 1024.f);
  float var = s2 * (1.f / 1024.f) - mu * mu;
  float rs = rsqrtf(var + 1e-5f);
  float4 gv = ((const float4*)g1)[tid];
  float4 bv = ((const float4*)b1)[tid];
  ushort4 o;
  o.x = f2bf((r0 - mu) * rs * gv.x + bv.x);
  o.y = f2bf((r1 - mu) * rs * gv.y + bv.y);
  o.z = f2bf((r2 - mu) * rs * gv.z + bv.z);
  o.w = f2bf((r3 - mu) * rs * gv.w + bv.w);
  ((ushort4*)(yb + (size_t)t * DM))[tid] = o;
}

// out = LN(y + ffn). grid TOK, 256 thr. ffn may alias out (row-local).
__global__ __launch_bounds__(256)
void ln2_kernel(const unsigned short* __restrict__ yb, const float* __restrict__ ffn,
                const float* __restrict__ g2, const float* __restrict__ b2,
                float* __restrict__ out)
{
  __shared__ float sm[4];
  int t = blockIdx.x, tid = threadIdx.x;
  ushort4 yv = ((const ushort4*)(yb + (size_t)t * DM))[tid];
  float4 fv = ((const float4*)(ffn + (size_t)t * DM))[tid];
  float r0 = bf2f(yv.x) + fv.x, r1 = bf2f(yv.y) + fv.y;
  float r2 = bf2f(yv.z) + fv.z, r3 = bf2f(yv.w) + fv.w;
  float s1 = block_sum(r0 + r1 + r2 + r3, sm);
  float s2 = block_sum(r0 * r0 + r1 * r1 + r2 * r2 + r3 * r3, sm);
  float mu = s1 * (1.f / 1024.f);
  float var = s2 * (1.f / 1024.f) - mu * mu;
  float rs = rsqrtf(var + 1e-5f);
  float4 gv = ((const float4*)g2)[tid];
  float4 bv = ((const float4*)b2)[tid];
  float4 o;
  o.x = (r0 - mu) * rs * gv.x + bv.x;
  o.y = (r1 - mu) * rs * gv.y + bv.y;
  o.z = (r2 - mu) * rs * gv.z + bv.z;
  o.w = (r3 - mu) * rs * gv.w + bv.w;
  ((float4*)(out + (size_t)t * DM))[tid] = o;
}

extern "C" void kernel_launch(void* const* d_in, const int* in_sizes, int n_in,
                              void* d_out, int out_size, void* d_ws, size_t ws_size,
                              hipStream_t stream)
{
  const float* x    = (const float*)d_in[0];
  const float* Wqkv = (const float*)d_in[1];
  const float* bqkv = (const float*)d_in[2];
  const float* Wg   = (const float*)d_in[3];
  const float* bg   = (const float*)d_in[4];
  const float* Wu   = (const float*)d_in[5];
  const float* bu   = (const float*)d_in[6];
  const float* Wd   = (const float*)d_in[7];
  const float* bd   = (const float*)d_in[8];
  const float* g1   = (const float*)d_in[9];
  const float* b1   = (const float*)d_in[10];
  const float* g2   = (const float*)d_in[11];
  const float* b2   = (const float*)d_in[12];
  float* out = (float*)d_out;

  // ---- workspace layout (~158.5 MiB total) ----
  char* ws = (char*)d_ws;
  size_t off = 0;
  auto alloc = [&](size_t bytes) {
    char* p = ws + off;
    off += (bytes + 255) & ~(size_t)255;
    return p;
  };
  unsigned short* WqkvT = (unsigned short*)alloc((size_t)NQKV * DM * 2);   //  6.3 MB
  unsigned short* WgT   = (unsigned short*)alloc((size_t)FFHP * DM * 2);   //  5.8 MB
  unsigned short* WuT   = (unsigned short*)alloc((size_t)FFHP * DM * 2);   //  5.8 MB
  unsigned short* WdT   = (unsigned short*)alloc((size_t)DM * FFHP * 2);   //  5.8 MB
  float*          ksum  = (float*)alloc((size_t)4 * DM * 4);               // 16 KB
  unsigned short* xbyb  = (unsigned short*)alloc((size_t)TOK * DM * 2);    // 32 MB (xb then yb)
  unsigned short* kvT   = (unsigned short*)alloc((size_t)4 * DM * DM * 2); //  8.4 MB
  char* R3 = alloc((size_t)3 * TOK * DM * 2);                              // 96 MB
  unsigned short* qp  = (unsigned short*)(R3);
  unsigned short* kpT = (unsigned short*)(R3 + (size_t)TOK * DM * 2);
  unsigned short* vT  = (unsigned short*)(R3 + (size_t)2 * TOK * DM * 2);
  unsigned short* gate = (unsigned short*)(R3);     // aliases qp/kpT (dead after ln1)
  unsigned short* xb = xbyb;                        // dead after QKV GEMM + ln1 read
  unsigned short* yb = xbyb;                        // born at ln1
  unsigned short* num = (unsigned short*)d_out;     // bf16 scratch in d_out; dead after ln1
  float* ffn = (float*)d_out;                       // fp32 scratch; ln2 reads+overwrites row-local

  dim3 blk(256);

  // 1. x -> bf16
  cvt_kernel<<<dim3(TOK * DM / 1024), blk, 0, stream>>>(x, xb, TOK * DM);
  // 2. weight transpose+convert (+pad)
  wtrans_kernel<<<dim3(32, 96), blk, 0, stream>>>(Wqkv, WqkvT, 1024, 3072, 3072, 1024);
  wtrans_kernel<<<dim3(32, 88), blk, 0, stream>>>(Wg, WgT, 1024, FFH, FFHP, 1024);
  wtrans_kernel<<<dim3(32, 88), blk, 0, stream>>>(Wu, WuT, 1024, FFH, FFHP, 1024);
  wtrans_kernel<<<dim3(88, 32), blk, 0, stream>>>(Wd, WdT, FFH, 1024, 1024, FFHP);
  // 3. QKV GEMM: qp[s][d] (elu+1), kpT[d][s] (elu+1), vT[d][s]
  gemm_kernel<M_QKV><<<dim3(NQKV / 128, TOK / 128), blk, 0, stream>>>(
      xb, WqkvT, 1024, 1024, 1024, 0, 0, 0, 0, qp, kpT, vT, bqkv, NQKV);
  // 4. k_sum[b][d]
  ksum_kernel<<<dim3(4096), blk, 0, stream>>>(kpT, ksum);
  // 5. kvT[b][e][d] = sum_s v[s,e] kp[s,d]
  gemm_kernel<M_BF16><<<dim3(8, 8, 4), blk, 0, stream>>>(
      vT, kpT, 4096, 4096, 4096, 1024,
      (long)DM * SEQ, (long)DM * SEQ, (long)DM * DM,
      kvT, nullptr, nullptr, nullptr, 0);
  // 6. num[b][s][e] = qp[s,:] . kv[:,e]  (BT = kvT) -> d_out (bf16)
  gemm_kernel<M_NUM><<<dim3(8, 32, 4), blk, 0, stream>>>(
      qp, kvT, 1024, 1024, 1024, 1024,
      (long)SEQ * DM, (long)DM * DM, (long)SEQ * DM,
      num, nullptr, nullptr, nullptr, 0);
  // 7. LN1 (fused den + attn + residual), y in bf16 (overwrites xb in place)
  ln1_kernel<<<dim3(TOK), blk, 0, stream>>>(xb, num, qp, ksum, g1, b1, yb);
  // 8. gate = y @ Wg + bg (bf16), into R3 (phase-1 buffers dead)
  gemm_kernel<M_BIAS_BF16><<<dim3(FFHP / 128, TOK / 128), blk, 0, stream>>>(
      yb, WgT, 1024, 1024, 1024, FFHP, 0, 0, 0, gate, nullptr, nullptr, bg, FFH);
  // 9. h = silu(gate) * (y @ Wu + bu), in-place over gate
  gemm_kernel<M_SWIGLU><<<dim3(FFHP / 128, TOK / 128), blk, 0, stream>>>(
      yb, WuT, 1024, 1024, 1024, FFHP, 0, 0, 0, gate, gate, nullptr, bu, FFH);
  // 10. ffn = h @ Wd + bd (fp32) -> d_out
  gemm_kernel<M_BIAS_F32><<<dim3(DM / 128, TOK / 128), blk, 0, stream>>>(
      gate, WdT, FFHP, FFHP, FFHP, DM, 0, 0, 0, ffn, nullptr, nullptr, bd, DM);
  // 11. out = LN(y + ffn)  (reads+overwrites d_out row-locally)
  ln2_kernel<<<dim3(TOK), blk, 0, stream>>>(yb, ffn, g2, b2, out);

  (void)in_sizes; (void)n_in; (void)out_size; (void)ws_size;
}

// Round 4
// 832.289 us; speedup vs baseline: 1.3572x; 1.1976x over previous
//
#include <hip/hip_runtime.h>

#define SEQ 4096
#define TOK 16384            // B*S
#define DM 1024
#define NQKV 3072
#define FFH 2730
#define FFHP 2816            // padded to multiple of 128

typedef __bf16 bf16x8 __attribute__((ext_vector_type(8)));
typedef float f32x4 __attribute__((ext_vector_type(4)));

__device__ __forceinline__ unsigned short f2bf(float f) {
  union { float f; unsigned u; } v; v.f = f;
  unsigned r = v.u + 0x7fffu + ((v.u >> 16) & 1u);
  return (unsigned short)(r >> 16);
}
__device__ __forceinline__ float bf2f(unsigned short h) {
  union { unsigned u; float f; } v; v.u = ((unsigned)h) << 16;
  return v.f;
}

__device__ __forceinline__ void xcd_swizzle(int& bx, int& by) {
  const int gx = gridDim.x, gy = gridDim.y;
  const int chunk = gy >> 3;            // power of 2 in all our launches
  const int csh = __ffs(chunk) - 1;
  const int lin = by * gx + bx;
  const int xcd = lin & 7, j = lin >> 3;
  by = xcd * chunk + (j & (chunk - 1));
  bx = j >> csh;
}

enum { M_QKV = 0, M_BF16 = 1, M_NUM = 2, M_BIAS_F32 = 5 };

// C[M,N] = A[M,K] (row-major) * BT[N,K]^T, 128x128 tile, BK=64, 4 waves,
// mfma_f32_16x16x32_bf16, global_load_lds(16B) staging, double-buffered LDS:
// per iter: waitcnt(prev loads) -> barrier -> issue next tile loads -> compute.
// XCD swizzle: XCD x owns contiguous M-chunk (A-tile stays in one XCD's L2).
// XOR bank swizzle: LDS[row][g] holds global k-block (g ^ (row&7)).
template<int MODE>
__global__ __launch_bounds__(256)
void gemm_kernel(const unsigned short* __restrict__ A,
                 const unsigned short* __restrict__ BT,
                 int K, int lda, int ldb, int ldc,
                 long zsA, long zsB, long zsC,
                 void* __restrict__ out0, void* __restrict__ out1, void* __restrict__ out2,
                 const float* __restrict__ bias, int nbias)
{
  __shared__ unsigned short As[2][128 * 64];
  __shared__ unsigned short Bs[2][128 * 64];
  const int tid  = threadIdx.x;
  const int wave = tid >> 6, lane = tid & 63;
  const int quad = lane >> 4, l16 = lane & 15;
  const int bz = blockIdx.z;
  int bx = blockIdx.x, by = blockIdx.y;
  xcd_swizzle(bx, by);

  const unsigned short* Ab = A + (size_t)zsA * bz + (size_t)by * 128 * lda;
  const unsigned short* Bb = BT + (size_t)zsB * bz + (size_t)bx * 128 * ldb;

  f32x4 acc[4][4] = {};

  const int srow   = lane >> 3;                        // 0..7 within 8-row chunk
  const int scol_g = (((lane & 7) ^ srow) * 8);        // XOR-swizzled global col block
  const int axor   = l16 & 7;

  auto stage = [&](int buf, int k0) {
#pragma unroll
    for (int j = 0; j < 4; ++j) {
      int c = wave * 4 + j;          // 16 chunks of 8 rows
      const unsigned short* sa = Ab + (size_t)(c * 8 + srow) * lda + k0 + scol_g;
      __builtin_amdgcn_global_load_lds((__attribute__((address_space(1))) void*)sa,
          (__attribute__((address_space(3))) void*)(As[buf] + c * 512), 16, 0, 0);
      const unsigned short* sb = Bb + (size_t)(c * 8 + srow) * ldb + k0 + scol_g;
      __builtin_amdgcn_global_load_lds((__attribute__((address_space(1))) void*)sb,
          (__attribute__((address_space(3))) void*)(Bs[buf] + c * 512), 16, 0, 0);
    }
  };

  const int NIT = K >> 6;
  stage(0, 0);
  int cur = 0;
  for (int it = 0; it < NIT; ++it) {
    __builtin_amdgcn_s_waitcnt(0);     // drain cur buffer's 8 loads
    __syncthreads();                   // all waves done with the other buffer
    if (it + 1 < NIT) stage(cur ^ 1, (it + 1) << 6);
#pragma unroll
    for (int kk = 0; kk < 64; kk += 32) {
      bf16x8 af[4], bfr[4];
#pragma unroll
      for (int mt = 0; mt < 4; ++mt)
        af[mt] = *(const bf16x8*)(As[cur] + ((wave >> 1) * 64 + mt * 16 + l16) * 64
                                     + ((((kk >> 3) + quad) ^ axor) * 8));
#pragma unroll
      for (int nt = 0; nt < 4; ++nt)
        bfr[nt] = *(const bf16x8*)(Bs[cur] + ((wave & 1) * 64 + nt * 16 + l16) * 64
                                      + ((((kk >> 3) + quad) ^ axor) * 8));
#pragma unroll
      for (int mt = 0; mt < 4; ++mt)
#pragma unroll
        for (int nt = 0; nt < 4; ++nt)
          acc[mt][nt] = __builtin_amdgcn_mfma_f32_16x16x32_bf16(af[mt], bfr[nt], acc[mt][nt], 0, 0, 0);
    }
    cur ^= 1;
  }

#pragma unroll
  for (int mt = 0; mt < 4; ++mt) {
#pragma unroll
    for (int nt = 0; nt < 4; ++nt) {
      const int r0 = by * 128 + (wave >> 1) * 64 + mt * 16 + quad * 4;
      const int c  = bx * 128 + (wave & 1) * 64 + nt * 16 + l16;
      float vals[4];
#pragma unroll
      for (int i = 0; i < 4; ++i) vals[i] = acc[mt][nt][i];

      if (MODE == M_QKV) {
        const int b = r0 >> 12, s0 = r0 & 4095;
#pragma unroll
        for (int i = 0; i < 4; ++i) vals[i] += bias[c];
        if (c < 1024) {
#pragma unroll
          for (int i = 0; i < 4; ++i) {
            float e = vals[i] > 0.f ? vals[i] + 1.f : __expf(vals[i]);
            ((unsigned short*)out0)[(size_t)(r0 + i) * DM + c] = f2bf(e);
          }
        } else if (c < 2048) {
          ushort4 o;
          float e0 = vals[0] > 0.f ? vals[0] + 1.f : __expf(vals[0]);
          float e1 = vals[1] > 0.f ? vals[1] + 1.f : __expf(vals[1]);
          float e2 = vals[2] > 0.f ? vals[2] + 1.f : __expf(vals[2]);
          float e3 = vals[3] > 0.f ? vals[3] + 1.f : __expf(vals[3]);
          o.x = f2bf(e0); o.y = f2bf(e1); o.z = f2bf(e2); o.w = f2bf(e3);
          *(ushort4*)((unsigned short*)out1 + (size_t)b * DM * SEQ + (size_t)(c - 1024) * SEQ + s0) = o;
        } else {
          ushort4 o;
          o.x = f2bf(vals[0]); o.y = f2bf(vals[1]); o.z = f2bf(vals[2]); o.w = f2bf(vals[3]);
          *(ushort4*)((unsigned short*)out2 + (size_t)b * DM * SEQ + (size_t)(c - 2048) * SEQ + s0) = o;
        }
      } else {
#pragma unroll
        for (int i = 0; i < 4; ++i) {
          const int r = r0 + i;
          float val = vals[i];
          if (MODE == M_BF16 || MODE == M_NUM) {
            ((unsigned short*)out0)[(size_t)zsC * bz + (size_t)r * ldc + c] = f2bf(val);
          } else { // M_BIAS_F32
            if (c < nbias) val += bias[c];
            ((float*)out0)[(size_t)r * ldc + c] = val;
          }
        }
      }
    }
  }
}

// Fused gate/up/SwiGLU: h = silu(y@Wg + bg) * (y@Wu + bu), written bf16 [TOK][FFHP].
// Tile 128M x 64N (per h-column), two B stages (Wg, Wu), double-buffered LDS.
__global__ __launch_bounds__(256)
void gateup_kernel(const unsigned short* __restrict__ A,
                   const unsigned short* __restrict__ BgT,
                   const unsigned short* __restrict__ BuT,
                   const float* __restrict__ bg, const float* __restrict__ bu,
                   unsigned short* __restrict__ h)
{
  __shared__ unsigned short As[2][128 * 64];
  __shared__ unsigned short Bgs[2][64 * 64];
  __shared__ unsigned short Bus[2][64 * 64];
  const int tid  = threadIdx.x;
  const int wave = tid >> 6, lane = tid & 63;
  const int quad = lane >> 4, l16 = lane & 15;
  const int wm = wave >> 1, wn = wave & 1;
  int bx = blockIdx.x, by = blockIdx.y;
  xcd_swizzle(bx, by);

  const unsigned short* Ab  = A + (size_t)by * 128 * DM;
  const unsigned short* Bgb = BgT + (size_t)bx * 64 * DM;
  const unsigned short* Bub = BuT + (size_t)bx * 64 * DM;

  f32x4 accg[4][2] = {};
  f32x4 accu[4][2] = {};

  const int srow   = lane >> 3;
  const int scol_g = (((lane & 7) ^ srow) * 8);
  const int axor   = l16 & 7;

  auto stage = [&](int buf, int k0) {
#pragma unroll
    for (int j = 0; j < 4; ++j) {
      int c = wave * 4 + j;          // 16 chunks of 8 rows of A
      const unsigned short* sa = Ab + (size_t)(c * 8 + srow) * DM + k0 + scol_g;
      __builtin_amdgcn_global_load_lds((__attribute__((address_space(1))) void*)sa,
          (__attribute__((address_space(3))) void*)(As[buf] + c * 512), 16, 0, 0);
    }
#pragma unroll
    for (int j = 0; j < 2; ++j) {
      int c = wave * 2 + j;          // 8 chunks of 8 rows of each B
      const unsigned short* sg = Bgb + (size_t)(c * 8 + srow) * DM + k0 + scol_g;
      __builtin_amdgcn_global_load_lds((__attribute__((address_space(1))) void*)sg,
          (__attribute__((address_space(3))) void*)(Bgs[buf] + c * 512), 16, 0, 0);
      const unsigned short* su = Bub + (size_t)(c * 8 + srow) * DM + k0 + scol_g;
      __builtin_amdgcn_global_load_lds((__attribute__((address_space(1))) void*)su,
          (__attribute__((address_space(3))) void*)(Bus[buf] + c * 512), 16, 0, 0);
    }
  };

  const int NIT = DM >> 6;   // 16
  stage(0, 0);
  int cur = 0;
  for (int it = 0; it < NIT; ++it) {
    __builtin_amdgcn_s_waitcnt(0);
    __syncthreads();
    if (it + 1 < NIT) stage(cur ^ 1, (it + 1) << 6);
#pragma unroll
    for (int kk = 0; kk < 64; kk += 32) {
      const int kb = (((kk >> 3) + quad) ^ axor) * 8;
      bf16x8 af[4], bgf[2], buf_[2];
#pragma unroll
      for (int mt = 0; mt < 4; ++mt)
        af[mt] = *(const bf16x8*)(As[cur] + (wm * 64 + mt * 16 + l16) * 64 + kb);
#pragma unroll
      for (int nt = 0; nt < 2; ++nt) {
        bgf[nt]  = *(const bf16x8*)(Bgs[cur] + (wn * 32 + nt * 16 + l16) * 64 + kb);
        buf_[nt] = *(const bf16x8*)(Bus[cur] + (wn * 32 + nt * 16 + l16) * 64 + kb);
      }
#pragma unroll
      for (int mt = 0; mt < 4; ++mt)
#pragma unroll
        for (int nt = 0; nt < 2; ++nt) {
          accg[mt][nt] = __builtin_amdgcn_mfma_f32_16x16x32_bf16(af[mt], bgf[nt],  accg[mt][nt], 0, 0, 0);
          accu[mt][nt] = __builtin_amdgcn_mfma_f32_16x16x32_bf16(af[mt], buf_[nt], accu[mt][nt], 0, 0, 0);
        }
    }
    cur ^= 1;
  }

#pragma unroll
  for (int mt = 0; mt < 4; ++mt) {
#pragma unroll
    for (int nt = 0; nt < 2; ++nt) {
      const int r0 = by * 128 + wm * 64 + mt * 16 + quad * 4;
      const int c  = bx * 64 + wn * 32 + nt * 16 + l16;
      const float bgv = (c < FFH) ? bg[c] : 0.f;
      const float buv = (c < FFH) ? bu[c] : 0.f;
#pragma unroll
      for (int i = 0; i < 4; ++i) {
        float g = accg[mt][nt][i] + bgv;
        float u = accu[mt][nt][i] + buv;
        float hv = g / (1.f + __expf(-g)) * u;
        h[(size_t)(r0 + i) * FFHP + c] = f2bf(hv);
      }
    }
  }
}

// fp32 -> bf16 convert, 4 elems/thread
__global__ __launch_bounds__(256)
void cvt_kernel(const float* __restrict__ in, unsigned short* __restrict__ out, int n)
{
  int i = (blockIdx.x * 256 + threadIdx.x) * 4;
  if (i < n) {
    float4 v = *(const float4*)(in + i);
    ushort4 o;
    o.x = f2bf(v.x); o.y = f2bf(v.y); o.z = f2bf(v.z); o.w = f2bf(v.w);
    *(ushort4*)(out + i) = o;
  }
}

// in fp32 [R][C] -> out bf16 [Cpad][Rpad], zero-filled pad. grid (Rpad/32, Cpad/32)
__global__ __launch_bounds__(256)
void wtrans_kernel(const float* __restrict__ in, unsigned short* __restrict__ out,
                   int R, int C, int Cpad, int Rpad)
{
  __shared__ float tile[32][33];
  int r0 = blockIdx.x * 32;   // in-row / out-col
  int c0 = blockIdx.y * 32;   // in-col / out-row
  int tid = threadIdx.x;
#pragma unroll
  for (int j = 0; j < 4; ++j) {
    int r = j * 8 + (tid >> 5), c = tid & 31;
    float v = 0.f;
    if (r0 + r < R && c0 + c < C) v = in[(size_t)(r0 + r) * C + c0 + c];
    tile[r][c] = v;
  }
  __syncthreads();
#pragma unroll
  for (int j = 0; j < 4; ++j) {
    int c = j * 8 + (tid >> 5), r = tid & 31;
    out[(size_t)(c0 + c) * Rpad + (r0 + r)] = f2bf(tile[r][c]);
  }
}

__device__ __forceinline__ float block_sum(float v, float* sm)
{
#pragma unroll
  for (int o = 32; o > 0; o >>= 1) v += __shfl_down(v, o, 64);
  int w = threadIdx.x >> 6;
  if ((threadIdx.x & 63) == 0) sm[w] = v;
  __syncthreads();
  float r = sm[0] + sm[1] + sm[2] + sm[3];
  __syncthreads();
  return r;
}

// row sums of kpT [4][1024][4096] -> ksum [4][1024]; grid 4096
__global__ __launch_bounds__(256)
void ksum_kernel(const unsigned short* __restrict__ kpT, float* __restrict__ ksum)
{
  __shared__ float sm[4];
  int row = blockIdx.x;
  const ushort4* src = (const ushort4*)(kpT + (size_t)row * SEQ);
  float s = 0.f;
#pragma unroll
  for (int j = 0; j < 4; ++j) {
    ushort4 v = src[threadIdx.x + j * 256];
    s += bf2f(v.x) + bf2f(v.y) + bf2f(v.z) + bf2f(v.w);
  }
  float tot = block_sum(s, sm);
  if (threadIdx.x == 0) ksum[row] = tot;
}

// y = LN(x + num/(den+eps)); den = qp . ksum  (fused). grid TOK, 256 thr
__global__ __launch_bounds__(256)
void ln1_kernel(const unsigned short* __restrict__ xb16, const unsigned short* __restrict__ num16,
                const unsigned short* __restrict__ qp, const float* __restrict__ ksum,
                const float* __restrict__ g1, const float* __restrict__ b1,
                unsigned short* __restrict__ yb)
{
  __shared__ float sm[4];
  int t = blockIdx.x, tid = threadIdx.x, b = t >> 12;
  ushort4 xv = ((const ushort4*)(xb16 + (size_t)t * DM))[tid];
  ushort4 nv = ((const ushort4*)(num16 + (size_t)t * DM))[tid];
  ushort4 qv = ((const ushort4*)(qp + (size_t)t * DM))[tid];
  float4 kv = ((const float4*)(ksum + (size_t)b * DM))[tid];
  float q0 = bf2f(qv.x), q1 = bf2f(qv.y), q2 = bf2f(qv.z), q3 = bf2f(qv.w);
  float den = block_sum(q0 * kv.x + q1 * kv.y + q2 * kv.z + q3 * kv.w, sm);
  float inv = 1.f / (den + 1e-6f);
  float r0 = bf2f(xv.x) + bf2f(nv.x) * inv, r1 = bf2f(xv.y) + bf2f(nv.y) * inv;
  float r2 = bf2f(xv.z) + bf2f(nv.z) * inv, r3 = bf2f(xv.w) + bf2f(nv.w) * inv;
  float s1 = block_sum(r0 + r1 + r2 + r3, sm);
  float s2 = block_sum(r0 * r0 + r1 * r1 + r2 * r2 + r3 * r3, sm);
  float mu = s1 * (1.f / 1024.f);
  float var = s2 * (1.f / 1024.f) - mu * mu;
  float rs = rsqrtf(var + 1e-5f);
  float4 gv = ((const float4*)g1)[tid];
  float4 bv = ((const float4*)b1)[tid];
  ushort4 o;
  o.x = f2bf((r0 - mu) * rs * gv.x + bv.x);
  o.y = f2bf((r1 - mu) * rs * gv.y + bv.y);
  o.z = f2bf((r2 - mu) * rs * gv.z + bv.z);
  o.w = f2bf((r3 - mu) * rs * gv.w + bv.w);
  ((ushort4*)(yb + (size_t)t * DM))[tid] = o;
}

// out = LN(y + ffn). grid TOK, 256 thr. ffn may alias out (row-local).
__global__ __launch_bounds__(256)
void ln2_kernel(const unsigned short* __restrict__ yb, const float* __restrict__ ffn,
                const float* __restrict__ g2, const float* __restrict__ b2,
                float* __restrict__ out)
{
  __shared__ float sm[4];
  int t = blockIdx.x, tid = threadIdx.x;
  ushort4 yv = ((const ushort4*)(yb + (size_t)t * DM))[tid];
  float4 fv = ((const float4*)(ffn + (size_t)t * DM))[tid];
  float r0 = bf2f(yv.x) + fv.x, r1 = bf2f(yv.y) + fv.y;
  float r2 = bf2f(yv.z) + fv.z, r3 = bf2f(yv.w) + fv.w;
  float s1 = block_sum(r0 + r1 + r2 + r3, sm);
  float s2 = block_sum(r0 * r0 + r1 * r1 + r2 * r2 + r3 * r3, sm);
  float mu = s1 * (1.f / 1024.f);
  float var = s2 * (1.f / 1024.f) - mu * mu;
  float rs = rsqrtf(var + 1e-5f);
  float4 gv = ((const float4*)g2)[tid];
  float4 bv = ((const float4*)b2)[tid];
  float4 o;
  o.x = (r0 - mu) * rs * gv.x + bv.x;
  o.y = (r1 - mu) * rs * gv.y + bv.y;
  o.z = (r2 - mu) * rs * gv.z + bv.z;
  o.w = (r3 - mu) * rs * gv.w + bv.w;
  ((float4*)(out + (size_t)t * DM))[tid] = o;
}

extern "C" void kernel_launch(void* const* d_in, const int* in_sizes, int n_in,
                              void* d_out, int out_size, void* d_ws, size_t ws_size,
                              hipStream_t stream)
{
  const float* x    = (const float*)d_in[0];
  const float* Wqkv = (const float*)d_in[1];
  const float* bqkv = (const float*)d_in[2];
  const float* Wg   = (const float*)d_in[3];
  const float* bg   = (const float*)d_in[4];
  const float* Wu   = (const float*)d_in[5];
  const float* bu   = (const float*)d_in[6];
  const float* Wd   = (const float*)d_in[7];
  const float* bd   = (const float*)d_in[8];
  const float* g1   = (const float*)d_in[9];
  const float* b1   = (const float*)d_in[10];
  const float* g2   = (const float*)d_in[11];
  const float* b2   = (const float*)d_in[12];
  float* out = (float*)d_out;

  // ---- workspace layout (~158.5 MiB total) ----
  char* ws = (char*)d_ws;
  size_t off = 0;
  auto alloc = [&](size_t bytes) {
    char* p = ws + off;
    off += (bytes + 255) & ~(size_t)255;
    return p;
  };
  unsigned short* WqkvT = (unsigned short*)alloc((size_t)NQKV * DM * 2);   //  6.3 MB
  unsigned short* WgT   = (unsigned short*)alloc((size_t)FFHP * DM * 2);   //  5.8 MB
  unsigned short* WuT   = (unsigned short*)alloc((size_t)FFHP * DM * 2);   //  5.8 MB
  unsigned short* WdT   = (unsigned short*)alloc((size_t)DM * FFHP * 2);   //  5.8 MB
  float*          ksum  = (float*)alloc((size_t)4 * DM * 4);               // 16 KB
  unsigned short* xbyb  = (unsigned short*)alloc((size_t)TOK * DM * 2);    // 32 MB (xb then yb)
  unsigned short* kvT   = (unsigned short*)alloc((size_t)4 * DM * DM * 2); //  8.4 MB
  char* R3 = alloc((size_t)3 * TOK * DM * 2);                              // 96 MB
  unsigned short* qp  = (unsigned short*)(R3);
  unsigned short* kpT = (unsigned short*)(R3 + (size_t)TOK * DM * 2);
  unsigned short* vT  = (unsigned short*)(R3 + (size_t)2 * TOK * DM * 2);
  unsigned short* hbuf = (unsigned short*)(R3);     // [TOK][FFHP] 92.3 MB, aliases qp/kpT/vT (dead after ln1)
  unsigned short* xb = xbyb;                        // dead after QKV GEMM + ln1 read
  unsigned short* yb = xbyb;                        // born at ln1 (in-place)
  unsigned short* num = (unsigned short*)d_out;     // bf16 scratch in d_out; dead after ln1
  float* ffn = (float*)d_out;                       // fp32 scratch; ln2 reads+overwrites row-local

  dim3 blk(256);

  // 1. x -> bf16
  cvt_kernel<<<dim3(TOK * DM / 1024), blk, 0, stream>>>(x, xb, TOK * DM);
  // 2. weight transpose+convert (+pad)
  wtrans_kernel<<<dim3(32, 96), blk, 0, stream>>>(Wqkv, WqkvT, 1024, 3072, 3072, 1024);
  wtrans_kernel<<<dim3(32, 88), blk, 0, stream>>>(Wg, WgT, 1024, FFH, FFHP, 1024);
  wtrans_kernel<<<dim3(32, 88), blk, 0, stream>>>(Wu, WuT, 1024, FFH, FFHP, 1024);
  wtrans_kernel<<<dim3(88, 32), blk, 0, stream>>>(Wd, WdT, FFH, 1024, 1024, FFHP);
  // 3. QKV GEMM: qp[s][d] (elu+1), kpT[d][s] (elu+1), vT[d][s]
  gemm_kernel<M_QKV><<<dim3(NQKV / 128, TOK / 128), blk, 0, stream>>>(
      xb, WqkvT, 1024, 1024, 1024, 0, 0, 0, 0, qp, kpT, vT, bqkv, NQKV);
  // 4. k_sum[b][d]
  ksum_kernel<<<dim3(4096), blk, 0, stream>>>(kpT, ksum);
  // 5. kvT[b][e][d] = sum_s v[s,e] kp[s,d]
  gemm_kernel<M_BF16><<<dim3(8, 8, 4), blk, 0, stream>>>(
      vT, kpT, 4096, 4096, 4096, 1024,
      (long)DM * SEQ, (long)DM * SEQ, (long)DM * DM,
      kvT, nullptr, nullptr, nullptr, 0);
  // 6. num[b][s][e] = qp[s,:] . kv[:,e]  (BT = kvT) -> d_out (bf16)
  gemm_kernel<M_NUM><<<dim3(8, 32, 4), blk, 0, stream>>>(
      qp, kvT, 1024, 1024, 1024, 1024,
      (long)SEQ * DM, (long)DM * DM, (long)SEQ * DM,
      num, nullptr, nullptr, nullptr, 0);
  // 7. LN1 (fused den + attn + residual), y in bf16 (overwrites xb in place)
  ln1_kernel<<<dim3(TOK), blk, 0, stream>>>(xb, num, qp, ksum, g1, b1, yb);
  // 8. h = silu(y@Wg+bg) * (y@Wu+bu), fused, bf16 [TOK][FFHP]
  gateup_kernel<<<dim3(FFHP / 64, TOK / 128), blk, 0, stream>>>(
      yb, WgT, WuT, bg, bu, hbuf);
  // 9. ffn = h @ Wd + bd (fp32) -> d_out
  gemm_kernel<M_BIAS_F32><<<dim3(DM / 128, TOK / 128), blk, 0, stream>>>(
      hbuf, WdT, FFHP, FFHP, FFHP, DM, 0, 0, 0, ffn, nullptr, nullptr, bd, DM);
  // 10. out = LN(y + ffn)  (reads+overwrites d_out row-locally)
  ln2_kernel<<<dim3(TOK), blk, 0, stream>>>(yb, ffn, g2, b2, out);

  (void)in_sizes; (void)n_in; (void)out_size; (void)ws_size;
}